// Round 8
// baseline (554.568 us; speedup 1.0000x reference)
//
#include <hip/hip_runtime.h>
#include <stdint.h>

typedef unsigned short u16;
typedef unsigned long long u64;
typedef __attribute__((ext_vector_type(8))) short bf16x8;
typedef __attribute__((ext_vector_type(4))) float f32x4;

#define DEV __device__ __forceinline__

DEV u16 f2bf(float f) {
  union { float f; unsigned u; } v; v.f = f;
  unsigned r = (v.u + 0x7fffu + ((v.u >> 16) & 1u)) >> 16;
  return (u16)r;
}

#define GLDS(g, l) __builtin_amdgcn_global_load_lds( \
    (const __attribute__((address_space(1))) void*)(g), \
    (__attribute__((address_space(3))) void*)(l), 16, 0, 0)

#define BAR() __builtin_amdgcn_s_barrier()
#define LGKM0() asm volatile("s_waitcnt lgkmcnt(0)" ::: "memory")
#define VMW(n) asm volatile("s_waitcnt vmcnt(" #n ")" ::: "memory")
#define SCHED0() __builtin_amdgcn_sched_barrier(0)

// ------- fused weight transpose+cast: [K][N] f32 -> [N][K] bf16, 4 segments --
__global__ __launch_bounds__(256) void k_transpose_all(
    const float* __restrict__ Wqkv, const float* __restrict__ Wout,
    const float* __restrict__ W1, const float* __restrict__ W2,
    u16* __restrict__ WqkvT, u16* __restrict__ WoutT,
    u16* __restrict__ W1T, u16* __restrict__ W2T) {
  int id = blockIdx.x;
  const float* in; u16* out; int K, N, nx, base;
  if (id < 3072)      { in = Wqkv; out = WqkvT; K = 1024; N = 3072; nx = 96;  base = 0; }
  else if (id < 4096) { in = Wout; out = WoutT; K = 1024; N = 1024; nx = 32;  base = 3072; }
  else if (id < 8192) { in = W1;   out = W1T;   K = 1024; N = 4096; nx = 128; base = 4096; }
  else                { in = W2;   out = W2T;   K = 4096; N = 1024; nx = 32;  base = 8192; }
  int seg = id - base, bx = seg % nx, by = seg / nx;
  __shared__ float tile[32][33];
  int tx = threadIdx.x & 31, ty = threadIdx.x >> 5;  // 32 x 8
#pragma unroll
  for (int r = 0; r < 32; r += 8)
    tile[ty + r][tx] = in[(size_t)(by * 32 + ty + r) * N + bx * 32 + tx];
  __syncthreads();
#pragma unroll
  for (int r = 0; r < 32; r += 8)
    out[(size_t)(bx * 32 + ty + r) * K + by * 32 + tx] = f2bf(tile[tx][ty + r]);
}

// ---------------- LayerNorm: x [rows][1024] f32 -> out bf16 ------------------
__global__ __launch_bounds__(256) void k_layernorm(
    const float* __restrict__ x, const float* __restrict__ gamma,
    const float* __restrict__ beta, u16* __restrict__ out) {
  int row = blockIdx.x, t = threadIdx.x;
  const float4 v = ((const float4*)(x + (size_t)row * 1024))[t];
  float sum = v.x + v.y + v.z + v.w;
  float sq = v.x * v.x + v.y * v.y + v.z * v.z + v.w * v.w;
#pragma unroll
  for (int o = 32; o >= 1; o >>= 1) {
    sum += __shfl_down(sum, o);
    sq += __shfl_down(sq, o);
  }
  __shared__ float red[8];
  if ((t & 63) == 0) { red[(t >> 6) * 2] = sum; red[(t >> 6) * 2 + 1] = sq; }
  __syncthreads();
  sum = red[0] + red[2] + red[4] + red[6];
  sq = red[1] + red[3] + red[5] + red[7];
  float mean = sum * (1.0f / 1024.0f);
  float var = sq * (1.0f / 1024.0f) - mean * mean;
  float rstd = rsqrtf(var + 1e-5f);
  float4 g = ((const float4*)gamma)[t];
  float4 b = ((const float4*)beta)[t];
  ushort4 o4;
  o4.x = f2bf(g.x * (v.x - mean) * rstd + b.x);
  o4.y = f2bf(g.y * (v.y - mean) * rstd + b.y);
  o4.z = f2bf(g.z * (v.z - mean) * rstd + b.z);
  o4.w = f2bf(g.w * (v.w - mean) * rstd + b.w);
  ((ushort4*)(out + (size_t)row * 1024))[t] = o4;
}

// ---------------- epilogues (r = M row; c0 = first of 4 consecutive N) -------
struct EpiQKV {  // scatter qkv: Q,K [B*H][S][64] bf16 ; VT [B*H][64][S] bf16
  u16 *Q, *K2, *VT;
  DEV void operator()(int r, int c0, const f32x4& v) const {
    int three = c0 >> 10, h = (c0 >> 6) & 15, hd = c0 & 63;
    int b = r >> 11, s = r & 2047;
    int bh = b * 16 + h;
    ushort4 o;
    o.x = f2bf(v[0]); o.y = f2bf(v[1]); o.z = f2bf(v[2]); o.w = f2bf(v[3]);
    if (three == 0)
      *(ushort4*)&Q[((size_t)bh * 2048 + s) * 64 + hd] = o;
    else if (three == 1)
      *(ushort4*)&K2[((size_t)bh * 2048 + s) * 64 + hd] = o;
    else {
      VT[((size_t)bh * 64 + hd + 0) * 2048 + s] = o.x;
      VT[((size_t)bh * 64 + hd + 1) * 2048 + s] = o.y;
      VT[((size_t)bh * 64 + hd + 2) * 2048 + s] = o.z;
      VT[((size_t)bh * 64 + hd + 3) * 2048 + s] = o.w;
    }
  }
};

struct EpiBiasResid {  // out f32 = v + bias[c] + resid[r*N+c]
  const float* bias; const float* resid; float* out; int N;
  DEV void operator()(int r, int c0, const f32x4& v) const {
    size_t idx = (size_t)r * N + c0;
    float4 bb = *(const float4*)&bias[c0];
    float4 rr = *(const float4*)&resid[idx];
    float4 o;
    o.x = v[0] + bb.x + rr.x; o.y = v[1] + bb.y + rr.y;
    o.z = v[2] + bb.z + rr.z; o.w = v[3] + bb.w + rr.w;
    *(float4*)&out[idx] = o;
  }
};

struct EpiBiasGelu {  // out bf16 = gelu_tanh(v + bias[c])
  const float* bias; u16* out; int N;
  DEV float gelu(float xx) const {
    float u = 0.7978845608f * (xx + 0.044715f * xx * xx * xx);
    float e = __expf(2.0f * u);
    float th = 1.0f - 2.0f / (e + 1.0f);
    return 0.5f * xx * (1.0f + th);
  }
  DEV void operator()(int r, int c0, const f32x4& v) const {
    float4 bb = *(const float4*)&bias[c0];
    ushort4 o;
    o.x = f2bf(gelu(v[0] + bb.x)); o.y = f2bf(gelu(v[1] + bb.y));
    o.z = f2bf(gelu(v[2] + bb.z)); o.w = f2bf(gelu(v[3] + bb.w));
    *(ushort4*)&out[(size_t)r * N + c0] = o;
  }
};

// ---------------- GEMM TN: A[M,K] bf16 K-contig, Bt[N,K] bf16 K-contig -------
// 128x128 tile, 256 thr (4 waves 2x2), BK=64 as TWO 32-K panels, DEPTH-2 dbuf
// (r5/r6-verified).  NEW (r8): XCD-aware block remap — each XCD owns a
// contiguous bn range so its B working set stays L2-resident (W2: 2 MB/XCD;
// W1: 4 MB; QKV: 0.75 MB), and the 2 co-resident blocks of a CU get adjacent
// ids -> same XCD, same bn -> shared B staging is an L2 hit.  Bijective:
// total%8==0 and gridDim.x==64 for all four launches.
#define STG8(tk, d) do { \
    GLDS(gA + (tk) * 64,                        &As[d][0][t * 8]); \
    GLDS(gA + (tk) * 64 + (size_t)64 * K,       &As[d][0][t * 8 + 2048]); \
    GLDS(gA + (tk) * 64 + 32,                   &As[d][1][t * 8]); \
    GLDS(gA + (tk) * 64 + 32 + (size_t)64 * K,  &As[d][1][t * 8 + 2048]); \
    GLDS(gB + (tk) * 64,                        &Bs[d][0][t * 8]); \
    GLDS(gB + (tk) * 64 + (size_t)64 * K,       &Bs[d][0][t * 8 + 2048]); \
    GLDS(gB + (tk) * 64 + 32,                   &Bs[d][1][t * 8]); \
    GLDS(gB + (tk) * 64 + 32 + (size_t)64 * K,  &Bs[d][1][t * 8 + 2048]); \
  } while (0)

template <typename Epi>
__global__ __launch_bounds__(256) void k_gemm_tn(
    const u16* __restrict__ A, const u16* __restrict__ Bt, int K, Epi epi) {
  __shared__ u16 As[2][2][128 * 32];  // [dbuf][panel][row*32+k], 32 KB
  __shared__ u16 Bs[2][2][128 * 32];  // 32 KB  -> 64 KB total
  const int t = threadIdx.x;
  int bm, bn;
  {
    int total = gridDim.x * gridDim.y;
    int id = blockIdx.x + gridDim.x * blockIdx.y;
    if (gridDim.x == 64 && !(total & 7)) {  // XCD-contiguous bn ranges
      int g = (id & 7) * (total >> 3) + (id >> 3);
      bm = g & 63;
      bn = g >> 6;
    } else { bm = blockIdx.x; bn = blockIdx.y; }
  }
  const int lane = t & 63, w = t >> 6;
  const int wm = w >> 1, wn = w & 1;
  const int quad = lane >> 4, l16 = lane & 15;
  f32x4 acc[4][4] = {};
  const u16* gA = A + (size_t)(bm * 128 + (t >> 2)) * K + (t & 3) * 8;
  const u16* gB = Bt + (size_t)(bn * 128 + (t >> 2)) * K + (t & 3) * 8;
  const int NT = K >> 6;  // K % 64 == 0; NT >= 2

  STG8(0, 0);
  STG8(1, 1);
  VMW(8);
  BAR();

  for (int T = 0; T < NT; ++T) {
    const int d = T & 1;
#pragma unroll
    for (int kk = 0; kk < 2; ++kk) {
      bf16x8 af[4], bfr[4];
#pragma unroll
      for (int mt = 0; mt < 4; ++mt)
        af[mt] = *(const bf16x8*)&As[d][kk][(wm * 64 + mt * 16 + l16) * 32 + quad * 8];
#pragma unroll
      for (int nt = 0; nt < 4; ++nt)
        bfr[nt] = *(const bf16x8*)&Bs[d][kk][(wn * 64 + nt * 16 + l16) * 32 + quad * 8];
#pragma unroll
      for (int mt = 0; mt < 4; ++mt)
#pragma unroll
        for (int nt = 0; nt < 4; ++nt)
          acc[mt][nt] = __builtin_amdgcn_mfma_f32_16x16x32_bf16(
              bfr[nt], af[mt], acc[mt][nt], 0, 0, 0);
    }
    SCHED0();
    BAR();      // all waves done reading buf[d]
    SCHED0();
    if (T + 2 < NT) {
      STG8(T + 2, d);   // overwrite buf[d] with tile T+2
      VMW(8);           // drain tile T+1 (issued one full iteration ago)
    } else {
      VMW(0);           // tail
    }
    BAR();
  }

  const int r0 = bm * 128 + wm * 64 + l16;       // M
  const int c0 = bn * 128 + wn * 64 + quad * 4;  // N (4 consecutive per lane)
#pragma unroll
  for (int mt = 0; mt < 4; ++mt)
#pragma unroll
    for (int nt = 0; nt < 4; ++nt)
      epi(r0 + mt * 16, c0 + nt * 16, acc[mt][nt]);
}

// ---------------- causal flash attention (S^T form, no-max online softmax) ---
// T14 async-STAGE split (r6 verified): K/V(kt+1) global->reg loads issue during
// tile kt's compute; VMW(0) lands them at the next write point.
#define PW 72  // u16 row stride: 144 B; 2-way banks on b128 reads (free)

#define ATT_LOAD(kr, vr, k0_) do { \
  _Pragma("unroll") for (int j = 0; j < 4; ++j) { \
    int ch = t + 256 * j, r = ch >> 4, cc = (ch & 15) * 4; \
    kr[j] = *(const u64*)(Kbase + (size_t)((k0_) + r) * 64 + cc); \
    vr[j] = *(const u64*)(Vbase + (size_t)r * 2048 + (k0_) + cc); \
  } } while (0)

#define ATT_WRITE(kr, vr) do { \
  _Pragma("unroll") for (int j = 0; j < 4; ++j) { \
    int ch = t + 256 * j, r = ch >> 4, cc = (ch & 15) * 4; \
    *(u64*)&Ks[r * PW + cc] = kr[j]; \
    *(u64*)&Vs[r * PW + cc] = vr[j]; \
  } } while (0)

__global__ __launch_bounds__(256) void k_attn(
    const u16* __restrict__ Qg, const u16* __restrict__ Kg,
    const u16* __restrict__ VTg, u16* __restrict__ ctx) {
  const int bh = blockIdx.x;
  const int qt = 31 - blockIdx.y;  // big blocks first for tail scheduling
  const int b = bh >> 4, h = bh & 15;
  const int t = threadIdx.x, lane = t & 63, w = t >> 6;
  const int quad = lane >> 4, l16 = lane & 15;
  const int q0 = qt * 64;
  __shared__ u16 Qs[64 * PW], Ks[64 * PW], Vs[64 * PW];
  __shared__ u16 Ps[4][16 * PW];
  __shared__ float l_lds[4][16];
  const u16* Qbase = Qg + (size_t)bh * (2048 * 64);
  const u16* Kbase = Kg + (size_t)bh * (2048 * 64);
  const u16* Vbase = VTg + (size_t)bh * (64 * 2048);
#pragma unroll
  for (int j = 0; j < 4; ++j) {
    int ch = t + 256 * j, r = ch >> 4, cc = (ch & 15) * 4;
    *(u64*)&Qs[r * PW + cc] = *(const u64*)(Qbase + (size_t)(q0 + r) * 64 + cc);
  }
  __syncthreads();
  bf16x8 qf0 = *(const bf16x8*)&Qs[(w * 16 + l16) * PW + quad * 8];
  bf16x8 qf1 = *(const bf16x8*)&Qs[(w * 16 + l16) * PW + 32 + quad * 8];
  const int qrow = q0 + w * 16 + l16;  // one q-row per lane
  const float c1 = 0.18033688011f;     // (1/8) * log2(e)
  float lsum = 0.f;
  f32x4 acco[4] = {};

  auto tile = [&](int kt) {
    const int k0 = kt * 64;
    f32x4 sacc[4] = {};
#pragma unroll
    for (int kk = 0; kk < 2; ++kk) {
      bf16x8 qf = kk ? qf1 : qf0;
#pragma unroll
      for (int nt = 0; nt < 4; ++nt) {
        bf16x8 kf = *(const bf16x8*)&Ks[(nt * 16 + l16) * PW + kk * 32 + quad * 8];
        sacc[nt] = __builtin_amdgcn_mfma_f32_16x16x32_bf16(kf, qf, sacc[nt], 0, 0, 0);
      }
    }
    const bool diag = (kt == qt);
    float ls = 0.f;
#pragma unroll
    for (int nt = 0; nt < 4; ++nt) {
      ushort4 o;
#pragma unroll
      for (int reg = 0; reg < 4; ++reg) {
        float p = __builtin_amdgcn_exp2f(sacc[nt][reg] * c1);  // bounded scores
        if (diag && (k0 + nt * 16 + quad * 4 + reg > qrow)) p = 0.f;
        ls += p;
        (&o.x)[reg] = f2bf(p);
      }
      *(ushort4*)&Ps[w][l16 * PW + nt * 16 + quad * 4] = o;  // P^T -> A-layout
    }
    ls += __shfl_xor(ls, 16);
    ls += __shfl_xor(ls, 32);
    lsum += ls;
#pragma unroll
    for (int kk = 0; kk < 2; ++kk) {
      bf16x8 pf = *(const bf16x8*)&Ps[w][l16 * PW + kk * 32 + quad * 8];
#pragma unroll
      for (int nt = 0; nt < 4; ++nt) {
        bf16x8 vf = *(const bf16x8*)&Vs[(nt * 16 + l16) * PW + kk * 32 + quad * 8];
        acco[nt] = __builtin_amdgcn_mfma_f32_16x16x32_bf16(pf, vf, acco[nt], 0, 0, 0);
      }
    }
  };

  u64 kra[4], vra[4], krb[4], vrb[4];
  ATT_LOAD(kra, vra, 0);
  int kt = 0;
  while (true) {
    VMW(0);             // set-a data landed (issued a full tile earlier)
    BAR();              // all waves done reading Ks/Vs from prev tile
    ATT_WRITE(kra, vra);
    if (kt + 1 <= qt) ATT_LOAD(krb, vrb, (kt + 1) * 64);  // prefetch, in flight
    LGKM0();            // ds_writes visible
    BAR();
    tile(kt);
    if (++kt > qt) break;
    VMW(0);
    BAR();
    ATT_WRITE(krb, vrb);
    if (kt + 1 <= qt) ATT_LOAD(kra, vra, (kt + 1) * 64);
    LGKM0();
    BAR();
    tile(kt);
    if (++kt > qt) break;
  }

  if (quad == 0) l_lds[w][l16] = lsum;  // same-wave DS ops are ordered
  float4 lv = *(const float4*)&l_lds[w][quad * 4];
  float inv[4];
  inv[0] = 1.0f / lv.x; inv[1] = 1.0f / lv.y;
  inv[2] = 1.0f / lv.z; inv[3] = 1.0f / lv.w;
#pragma unroll
  for (int nt = 0; nt < 4; ++nt)
#pragma unroll
    for (int reg = 0; reg < 4; ++reg) {
      float o = acco[nt][reg] * inv[reg];
      int q = q0 + w * 16 + quad * 4 + reg;
      ctx[((size_t)(b * 2048 + q)) * 1024 + h * 64 + nt * 16 + l16] = f2bf(o);
    }
}

// ---------------- orchestration ----------------------------------------------
extern "C" void kernel_launch(void* const* d_in, const int* in_sizes, int n_in,
                              void* d_out, int out_size, void* d_ws, size_t ws_size,
                              hipStream_t stream) {
  (void)in_sizes; (void)n_in; (void)out_size; (void)ws_size;
  const float* x    = (const float*)d_in[0];
  const float* Wqkv = (const float*)d_in[1];
  const float* Wout = (const float*)d_in[2];
  const float* bout = (const float*)d_in[3];
  const float* W1   = (const float*)d_in[4];
  const float* b1   = (const float*)d_in[5];
  const float* W2   = (const float*)d_in[6];
  const float* b2   = (const float*)d_in[7];
  const float* g1   = (const float*)d_in[8];
  const float* s1   = (const float*)d_in[9];
  const float* g2   = (const float*)d_in[10];
  const float* s2   = (const float*)d_in[11];

  char* ws = (char*)d_ws;
  u16*   WqkvT = (u16*)(ws + 0);           //  6291456 B
  u16*   WoutT = (u16*)(ws + 6291456);     //  2097152
  u16*   W1T   = (u16*)(ws + 8388608);     //  8388608
  u16*   W2T   = (u16*)(ws + 16777216);    //  8388608
  float* x1    = (float*)(ws + 25165824);  // 33554432
  u16*   h12   = (u16*)(ws + 58720256);    // 16777216  (h1, later h2)
  u16*   Qb    = (u16*)(ws + 75497472);    // 16777216
  u16*   Kb    = (u16*)(ws + 92274688);    // 16777216
  u16*   VTb   = (u16*)(ws + 109051904);   // 16777216
  u16*   ctx   = (u16*)(ws + 125829120);   // 16777216  -> total 142606336
  u16*   a1    = (u16*)(ws + 75497472);    // 67108864, aliases Q..ctx (dead)

  k_transpose_all<<<12288, 256, 0, stream>>>(Wqkv, Wout, W1, W2,
                                             WqkvT, WoutT, W1T, W2T);

  k_layernorm<<<8192, 256, 0, stream>>>(x, g1, s1, h12);
  k_gemm_tn<<<dim3(64, 24), 256, 0, stream>>>(h12, WqkvT, 1024,
                                              EpiQKV{Qb, Kb, VTb});
  k_attn<<<dim3(64, 32), 256, 0, stream>>>(Qb, Kb, VTb, ctx);
  k_gemm_tn<<<dim3(64, 8), 256, 0, stream>>>(ctx, WoutT, 1024,
                                             EpiBiasResid{bout, x, x1, 1024});
  k_layernorm<<<8192, 256, 0, stream>>>(x1, g2, s2, h12);
  k_gemm_tn<<<dim3(64, 32), 256, 0, stream>>>(h12, W1T, 1024,
                                              EpiBiasGelu{b1, a1, 4096});
  k_gemm_tn<<<dim3(64, 8), 256, 0, stream>>>(a1, W2T, 4096,
                                             EpiBiasResid{b2, x1, (float*)d_out, 1024});
}

// Round 9
// 532.553 us; speedup vs baseline: 1.0413x; 1.0413x over previous
//
#include <hip/hip_runtime.h>
#include <stdint.h>

typedef unsigned short u16;
typedef unsigned long long u64;
typedef __attribute__((ext_vector_type(8))) short bf16x8;
typedef __attribute__((ext_vector_type(4))) float f32x4;

#define DEV __device__ __forceinline__

DEV u16 f2bf(float f) {
  union { float f; unsigned u; } v; v.f = f;
  unsigned r = (v.u + 0x7fffu + ((v.u >> 16) & 1u)) >> 16;
  return (u16)r;
}

#define GLDS(g, l) __builtin_amdgcn_global_load_lds( \
    (const __attribute__((address_space(1))) void*)(g), \
    (__attribute__((address_space(3))) void*)(l), 16, 0, 0)

#define BAR() __builtin_amdgcn_s_barrier()
#define LGKM0() asm volatile("s_waitcnt lgkmcnt(0)" ::: "memory")
#define VMW(n) asm volatile("s_waitcnt vmcnt(" #n ")" ::: "memory")
#define SCHED0() __builtin_amdgcn_sched_barrier(0)

// ------- fused weight transpose+cast: [K][N] f32 -> [N][K] bf16, 4 segments --
__global__ __launch_bounds__(256) void k_transpose_all(
    const float* __restrict__ Wqkv, const float* __restrict__ Wout,
    const float* __restrict__ W1, const float* __restrict__ W2,
    u16* __restrict__ WqkvT, u16* __restrict__ WoutT,
    u16* __restrict__ W1T, u16* __restrict__ W2T) {
  int id = blockIdx.x;
  const float* in; u16* out; int K, N, nx, base;
  if (id < 3072)      { in = Wqkv; out = WqkvT; K = 1024; N = 3072; nx = 96;  base = 0; }
  else if (id < 4096) { in = Wout; out = WoutT; K = 1024; N = 1024; nx = 32;  base = 3072; }
  else if (id < 8192) { in = W1;   out = W1T;   K = 1024; N = 4096; nx = 128; base = 4096; }
  else                { in = W2;   out = W2T;   K = 4096; N = 1024; nx = 32;  base = 8192; }
  int seg = id - base, bx = seg % nx, by = seg / nx;
  __shared__ float tile[32][33];
  int tx = threadIdx.x & 31, ty = threadIdx.x >> 5;  // 32 x 8
#pragma unroll
  for (int r = 0; r < 32; r += 8)
    tile[ty + r][tx] = in[(size_t)(by * 32 + ty + r) * N + bx * 32 + tx];
  __syncthreads();
#pragma unroll
  for (int r = 0; r < 32; r += 8)
    out[(size_t)(bx * 32 + ty + r) * K + by * 32 + tx] = f2bf(tile[tx][ty + r]);
}

// ---------------- LayerNorm: x [rows][1024] f32 -> out bf16 ------------------
__global__ __launch_bounds__(256) void k_layernorm(
    const float* __restrict__ x, const float* __restrict__ gamma,
    const float* __restrict__ beta, u16* __restrict__ out) {
  int row = blockIdx.x, t = threadIdx.x;
  const float4 v = ((const float4*)(x + (size_t)row * 1024))[t];
  float sum = v.x + v.y + v.z + v.w;
  float sq = v.x * v.x + v.y * v.y + v.z * v.z + v.w * v.w;
#pragma unroll
  for (int o = 32; o >= 1; o >>= 1) {
    sum += __shfl_down(sum, o);
    sq += __shfl_down(sq, o);
  }
  __shared__ float red[8];
  if ((t & 63) == 0) { red[(t >> 6) * 2] = sum; red[(t >> 6) * 2 + 1] = sq; }
  __syncthreads();
  sum = red[0] + red[2] + red[4] + red[6];
  sq = red[1] + red[3] + red[5] + red[7];
  float mean = sum * (1.0f / 1024.0f);
  float var = sq * (1.0f / 1024.0f) - mean * mean;
  float rstd = rsqrtf(var + 1e-5f);
  float4 g = ((const float4*)gamma)[t];
  float4 b = ((const float4*)beta)[t];
  ushort4 o4;
  o4.x = f2bf(g.x * (v.x - mean) * rstd + b.x);
  o4.y = f2bf(g.y * (v.y - mean) * rstd + b.y);
  o4.z = f2bf(g.z * (v.z - mean) * rstd + b.z);
  o4.w = f2bf(g.w * (v.w - mean) * rstd + b.w);
  ((ushort4*)(out + (size_t)row * 1024))[t] = o4;
}

// ---------------- epilogues (r = M row; c0 = first of 4 consecutive N) -------
struct EpiQKV {  // scatter qkv: Q,K [B*H][S][64] bf16 ; VT [B*H][64][S] bf16
  u16 *Q, *K2, *VT;
  DEV void operator()(int r, int c0, const f32x4& v) const {
    int three = c0 >> 10, h = (c0 >> 6) & 15, hd = c0 & 63;
    int b = r >> 11, s = r & 2047;
    int bh = b * 16 + h;
    ushort4 o;
    o.x = f2bf(v[0]); o.y = f2bf(v[1]); o.z = f2bf(v[2]); o.w = f2bf(v[3]);
    if (three == 0)
      *(ushort4*)&Q[((size_t)bh * 2048 + s) * 64 + hd] = o;
    else if (three == 1)
      *(ushort4*)&K2[((size_t)bh * 2048 + s) * 64 + hd] = o;
    else {
      VT[((size_t)bh * 64 + hd + 0) * 2048 + s] = o.x;
      VT[((size_t)bh * 64 + hd + 1) * 2048 + s] = o.y;
      VT[((size_t)bh * 64 + hd + 2) * 2048 + s] = o.z;
      VT[((size_t)bh * 64 + hd + 3) * 2048 + s] = o.w;
    }
  }
};

struct EpiBiasResid {  // out f32 = v + bias[c] + resid[r*N+c]
  const float* bias; const float* resid; float* out; int N;
  DEV void operator()(int r, int c0, const f32x4& v) const {
    size_t idx = (size_t)r * N + c0;
    float4 bb = *(const float4*)&bias[c0];
    float4 rr = *(const float4*)&resid[idx];
    float4 o;
    o.x = v[0] + bb.x + rr.x; o.y = v[1] + bb.y + rr.y;
    o.z = v[2] + bb.z + rr.z; o.w = v[3] + bb.w + rr.w;
    *(float4*)&out[idx] = o;
  }
};

struct EpiBiasGelu {  // out bf16 = gelu_tanh(v + bias[c])
  const float* bias; u16* out; int N;
  DEV float gelu(float xx) const {
    float u = 0.7978845608f * (xx + 0.044715f * xx * xx * xx);
    float e = __expf(2.0f * u);
    float th = 1.0f - 2.0f / (e + 1.0f);
    return 0.5f * xx * (1.0f + th);
  }
  DEV void operator()(int r, int c0, const f32x4& v) const {
    float4 bb = *(const float4*)&bias[c0];
    ushort4 o;
    o.x = f2bf(gelu(v[0] + bb.x)); o.y = f2bf(gelu(v[1] + bb.y));
    o.z = f2bf(gelu(v[2] + bb.z)); o.w = f2bf(gelu(v[3] + bb.w));
    *(ushort4*)&out[(size_t)r * N + c0] = o;
  }
};

// ---------------- GEMM TN: A[M,K] bf16 K-contig, Bt[N,K] bf16 K-contig -------
// 128x128 tile, 256 thr (4 waves 2x2), BK=64 as TWO 32-K panels, DEPTH-2 dbuf
// (r5/r6-verified).  NOTE r8 lesson: do NOT XCD-remap this grid — bm-fastest
// dispatch makes co-scheduled blocks share the same bn band, so A streams
// through HBM once for the whole machine; the remap cost 4.5x FETCH_SIZE.
#define STG8(tk, d) do { \
    GLDS(gA + (tk) * 64,                        &As[d][0][t * 8]); \
    GLDS(gA + (tk) * 64 + (size_t)64 * K,       &As[d][0][t * 8 + 2048]); \
    GLDS(gA + (tk) * 64 + 32,                   &As[d][1][t * 8]); \
    GLDS(gA + (tk) * 64 + 32 + (size_t)64 * K,  &As[d][1][t * 8 + 2048]); \
    GLDS(gB + (tk) * 64,                        &Bs[d][0][t * 8]); \
    GLDS(gB + (tk) * 64 + (size_t)64 * K,       &Bs[d][0][t * 8 + 2048]); \
    GLDS(gB + (tk) * 64 + 32,                   &Bs[d][1][t * 8]); \
    GLDS(gB + (tk) * 64 + 32 + (size_t)64 * K,  &Bs[d][1][t * 8 + 2048]); \
  } while (0)

template <typename Epi>
__global__ __launch_bounds__(256) void k_gemm_tn(
    const u16* __restrict__ A, const u16* __restrict__ Bt, int K, Epi epi) {
  __shared__ u16 As[2][2][128 * 32];  // [dbuf][panel][row*32+k], 32 KB
  __shared__ u16 Bs[2][2][128 * 32];  // 32 KB  -> 64 KB total
  const int t = threadIdx.x;
  const int bm = blockIdx.x, bn = blockIdx.y;
  const int lane = t & 63, w = t >> 6;
  const int wm = w >> 1, wn = w & 1;
  const int quad = lane >> 4, l16 = lane & 15;
  f32x4 acc[4][4] = {};
  const u16* gA = A + (size_t)(bm * 128 + (t >> 2)) * K + (t & 3) * 8;
  const u16* gB = Bt + (size_t)(bn * 128 + (t >> 2)) * K + (t & 3) * 8;
  const int NT = K >> 6;  // K % 64 == 0; NT >= 2

  STG8(0, 0);
  STG8(1, 1);
  VMW(8);
  BAR();

  for (int T = 0; T < NT; ++T) {
    const int d = T & 1;
#pragma unroll
    for (int kk = 0; kk < 2; ++kk) {
      bf16x8 af[4], bfr[4];
#pragma unroll
      for (int mt = 0; mt < 4; ++mt)
        af[mt] = *(const bf16x8*)&As[d][kk][(wm * 64 + mt * 16 + l16) * 32 + quad * 8];
#pragma unroll
      for (int nt = 0; nt < 4; ++nt)
        bfr[nt] = *(const bf16x8*)&Bs[d][kk][(wn * 64 + nt * 16 + l16) * 32 + quad * 8];
#pragma unroll
      for (int mt = 0; mt < 4; ++mt)
#pragma unroll
        for (int nt = 0; nt < 4; ++nt)
          acc[mt][nt] = __builtin_amdgcn_mfma_f32_16x16x32_bf16(
              bfr[nt], af[mt], acc[mt][nt], 0, 0, 0);
    }
    SCHED0();
    BAR();      // all waves done reading buf[d]
    SCHED0();
    if (T + 2 < NT) {
      STG8(T + 2, d);   // overwrite buf[d] with tile T+2
      VMW(8);           // drain tile T+1 (issued one full iteration ago)
    } else {
      VMW(0);           // tail
    }
    BAR();
  }

  const int r0 = bm * 128 + wm * 64 + l16;       // M
  const int c0 = bn * 128 + wn * 64 + quad * 4;  // N (4 consecutive per lane)
#pragma unroll
  for (int mt = 0; mt < 4; ++mt)
#pragma unroll
    for (int nt = 0; nt < 4; ++nt)
      epi(r0 + mt * 16, c0 + nt * 16, acc[mt][nt]);
}

// ---------------- causal flash attention (S^T form, no-max online softmax) ---
// T14 async-STAGE split (r6 verified).  r9: + T5 setprio around MFMA clusters
// (m191: +4-7% attn) and T12 v_cvt_pk_bf16_f32 for P->bf16 (replaces 16
// 5-op manual f2bf with 8 single-instr packs; same RNE rounding, same 8B
// aligned stores -- all Ps offset terms are 8B multiples).
#define PW 72  // u16 row stride: 144 B; 2-way banks on b128 reads (free)

#define ATT_LOAD(kr, vr, k0_) do { \
  _Pragma("unroll") for (int j = 0; j < 4; ++j) { \
    int ch = t + 256 * j, r = ch >> 4, cc = (ch & 15) * 4; \
    kr[j] = *(const u64*)(Kbase + (size_t)((k0_) + r) * 64 + cc); \
    vr[j] = *(const u64*)(Vbase + (size_t)r * 2048 + (k0_) + cc); \
  } } while (0)

#define ATT_WRITE(kr, vr) do { \
  _Pragma("unroll") for (int j = 0; j < 4; ++j) { \
    int ch = t + 256 * j, r = ch >> 4, cc = (ch & 15) * 4; \
    *(u64*)&Ks[r * PW + cc] = kr[j]; \
    *(u64*)&Vs[r * PW + cc] = vr[j]; \
  } } while (0)

__global__ __launch_bounds__(256) void k_attn(
    const u16* __restrict__ Qg, const u16* __restrict__ Kg,
    const u16* __restrict__ VTg, u16* __restrict__ ctx) {
  const int bh = blockIdx.x;
  const int qt = 31 - blockIdx.y;  // big blocks first for tail scheduling
  const int b = bh >> 4, h = bh & 15;
  const int t = threadIdx.x, lane = t & 63, w = t >> 6;
  const int quad = lane >> 4, l16 = lane & 15;
  const int q0 = qt * 64;
  __shared__ u16 Qs[64 * PW], Ks[64 * PW], Vs[64 * PW];
  __shared__ u16 Ps[4][16 * PW];
  __shared__ float l_lds[4][16];
  const u16* Qbase = Qg + (size_t)bh * (2048 * 64);
  const u16* Kbase = Kg + (size_t)bh * (2048 * 64);
  const u16* Vbase = VTg + (size_t)bh * (64 * 2048);
#pragma unroll
  for (int j = 0; j < 4; ++j) {
    int ch = t + 256 * j, r = ch >> 4, cc = (ch & 15) * 4;
    *(u64*)&Qs[r * PW + cc] = *(const u64*)(Qbase + (size_t)(q0 + r) * 64 + cc);
  }
  __syncthreads();
  bf16x8 qf0 = *(const bf16x8*)&Qs[(w * 16 + l16) * PW + quad * 8];
  bf16x8 qf1 = *(const bf16x8*)&Qs[(w * 16 + l16) * PW + 32 + quad * 8];
  const int qrow = q0 + w * 16 + l16;  // one q-row per lane
  const float c1 = 0.18033688011f;     // (1/8) * log2(e)
  float lsum = 0.f;
  f32x4 acco[4] = {};

  auto tile = [&](int kt) {
    const int k0 = kt * 64;
    f32x4 sacc[4] = {};
    __builtin_amdgcn_s_setprio(1);
#pragma unroll
    for (int kk = 0; kk < 2; ++kk) {
      bf16x8 qf = kk ? qf1 : qf0;
#pragma unroll
      for (int nt = 0; nt < 4; ++nt) {
        bf16x8 kf = *(const bf16x8*)&Ks[(nt * 16 + l16) * PW + kk * 32 + quad * 8];
        sacc[nt] = __builtin_amdgcn_mfma_f32_16x16x32_bf16(kf, qf, sacc[nt], 0, 0, 0);
      }
    }
    __builtin_amdgcn_s_setprio(0);
    const bool diag = (kt == qt);
    float ls = 0.f;
#pragma unroll
    for (int nt = 0; nt < 4; ++nt) {
      float p0, p1, p2, p3;
      p0 = __builtin_amdgcn_exp2f(sacc[nt][0] * c1);
      p1 = __builtin_amdgcn_exp2f(sacc[nt][1] * c1);
      p2 = __builtin_amdgcn_exp2f(sacc[nt][2] * c1);
      p3 = __builtin_amdgcn_exp2f(sacc[nt][3] * c1);
      if (diag) {  // causal mask on the diagonal tile only
        int kbase = k0 + nt * 16 + quad * 4;
        if (kbase + 0 > qrow) p0 = 0.f;
        if (kbase + 1 > qrow) p1 = 0.f;
        if (kbase + 2 > qrow) p2 = 0.f;
        if (kbase + 3 > qrow) p3 = 0.f;
      }
      ls += (p0 + p1) + (p2 + p3);
      unsigned pk0, pk1;
      asm("v_cvt_pk_bf16_f32 %0, %1, %2" : "=v"(pk0) : "v"(p0), "v"(p1));
      asm("v_cvt_pk_bf16_f32 %0, %1, %2" : "=v"(pk1) : "v"(p2), "v"(p3));
      uint2 pp; pp.x = pk0; pp.y = pk1;
      *(uint2*)&Ps[w][l16 * PW + nt * 16 + quad * 4] = pp;  // P^T -> A-layout
    }
    ls += __shfl_xor(ls, 16);
    ls += __shfl_xor(ls, 32);
    lsum += ls;
    __builtin_amdgcn_s_setprio(1);
#pragma unroll
    for (int kk = 0; kk < 2; ++kk) {
      bf16x8 pf = *(const bf16x8*)&Ps[w][l16 * PW + kk * 32 + quad * 8];
#pragma unroll
      for (int nt = 0; nt < 4; ++nt) {
        bf16x8 vf = *(const bf16x8*)&Vs[(nt * 16 + l16) * PW + kk * 32 + quad * 8];
        acco[nt] = __builtin_amdgcn_mfma_f32_16x16x32_bf16(pf, vf, acco[nt], 0, 0, 0);
      }
    }
    __builtin_amdgcn_s_setprio(0);
  };

  u64 kra[4], vra[4], krb[4], vrb[4];
  ATT_LOAD(kra, vra, 0);
  int kt = 0;
  while (true) {
    VMW(0);             // set-a data landed (issued a full tile earlier)
    BAR();              // all waves done reading Ks/Vs from prev tile
    ATT_WRITE(kra, vra);
    if (kt + 1 <= qt) ATT_LOAD(krb, vrb, (kt + 1) * 64);  // prefetch, in flight
    LGKM0();            // ds_writes visible
    BAR();
    tile(kt);
    if (++kt > qt) break;
    VMW(0);
    BAR();
    ATT_WRITE(krb, vrb);
    if (kt + 1 <= qt) ATT_LOAD(kra, vra, (kt + 1) * 64);
    LGKM0();
    BAR();
    tile(kt);
    if (++kt > qt) break;
  }

  if (quad == 0) l_lds[w][l16] = lsum;  // same-wave DS ops are ordered
  float4 lv = *(const float4*)&l_lds[w][quad * 4];
  float inv[4];
  inv[0] = 1.0f / lv.x; inv[1] = 1.0f / lv.y;
  inv[2] = 1.0f / lv.z; inv[3] = 1.0f / lv.w;
#pragma unroll
  for (int nt = 0; nt < 4; ++nt)
#pragma unroll
    for (int reg = 0; reg < 4; ++reg) {
      float o = acco[nt][reg] * inv[reg];
      int q = q0 + w * 16 + quad * 4 + reg;
      ctx[((size_t)(b * 2048 + q)) * 1024 + h * 64 + nt * 16 + l16] = f2bf(o);
    }
}

// ---------------- orchestration ----------------------------------------------
extern "C" void kernel_launch(void* const* d_in, const int* in_sizes, int n_in,
                              void* d_out, int out_size, void* d_ws, size_t ws_size,
                              hipStream_t stream) {
  (void)in_sizes; (void)n_in; (void)out_size; (void)ws_size;
  const float* x    = (const float*)d_in[0];
  const float* Wqkv = (const float*)d_in[1];
  const float* Wout = (const float*)d_in[2];
  const float* bout = (const float*)d_in[3];
  const float* W1   = (const float*)d_in[4];
  const float* b1   = (const float*)d_in[5];
  const float* W2   = (const float*)d_in[6];
  const float* b2   = (const float*)d_in[7];
  const float* g1   = (const float*)d_in[8];
  const float* s1   = (const float*)d_in[9];
  const float* g2   = (const float*)d_in[10];
  const float* s2   = (const float*)d_in[11];

  char* ws = (char*)d_ws;
  u16*   WqkvT = (u16*)(ws + 0);           //  6291456 B
  u16*   WoutT = (u16*)(ws + 6291456);     //  2097152
  u16*   W1T   = (u16*)(ws + 8388608);     //  8388608
  u16*   W2T   = (u16*)(ws + 16777216);    //  8388608
  float* x1    = (float*)(ws + 25165824);  // 33554432
  u16*   h12   = (u16*)(ws + 58720256);    // 16777216  (h1, later h2)
  u16*   Qb    = (u16*)(ws + 75497472);    // 16777216
  u16*   Kb    = (u16*)(ws + 92274688);    // 16777216
  u16*   VTb   = (u16*)(ws + 109051904);   // 16777216
  u16*   ctx   = (u16*)(ws + 125829120);   // 16777216  -> total 142606336
  u16*   a1    = (u16*)(ws + 75497472);    // 67108864, aliases Q..ctx (dead)

  k_transpose_all<<<12288, 256, 0, stream>>>(Wqkv, Wout, W1, W2,
                                             WqkvT, WoutT, W1T, W2T);

  k_layernorm<<<8192, 256, 0, stream>>>(x, g1, s1, h12);
  k_gemm_tn<<<dim3(64, 24), 256, 0, stream>>>(h12, WqkvT, 1024,
                                              EpiQKV{Qb, Kb, VTb});
  k_attn<<<dim3(64, 32), 256, 0, stream>>>(Qb, Kb, VTb, ctx);
  k_gemm_tn<<<dim3(64, 8), 256, 0, stream>>>(ctx, WoutT, 1024,
                                             EpiBiasResid{bout, x, x1, 1024});
  k_layernorm<<<8192, 256, 0, stream>>>(x1, g2, s2, h12);
  k_gemm_tn<<<dim3(64, 32), 256, 0, stream>>>(h12, W1T, 1024,
                                              EpiBiasGelu{b1, a1, 4096});
  k_gemm_tn<<<dim3(64, 8), 256, 0, stream>>>(a1, W2T, 4096,
                                             EpiBiasResid{b2, x1, (float*)d_out, 1024});
}

// Round 10
// 523.297 us; speedup vs baseline: 1.0598x; 1.0177x over previous
//
#include <hip/hip_runtime.h>
#include <stdint.h>

typedef unsigned short u16;
typedef unsigned long long u64;
typedef __attribute__((ext_vector_type(8))) short bf16x8;
typedef __attribute__((ext_vector_type(4))) float f32x4;

#define DEV __device__ __forceinline__

DEV u16 f2bf(float f) {
  union { float f; unsigned u; } v; v.f = f;
  unsigned r = (v.u + 0x7fffu + ((v.u >> 16) & 1u)) >> 16;
  return (u16)r;
}

#define GLDS(g, l) __builtin_amdgcn_global_load_lds( \
    (const __attribute__((address_space(1))) void*)(g), \
    (__attribute__((address_space(3))) void*)(l), 16, 0, 0)

#define BAR() __builtin_amdgcn_s_barrier()
#define LGKM0() asm volatile("s_waitcnt lgkmcnt(0)" ::: "memory")
#define VMW(n) asm volatile("s_waitcnt vmcnt(" #n ")" ::: "memory")
#define SCHED0() __builtin_amdgcn_sched_barrier(0)

// ------- fused weight transpose+cast: [K][N] f32 -> [N][K] bf16, 4 segments --
__global__ __launch_bounds__(256) void k_transpose_all(
    const float* __restrict__ Wqkv, const float* __restrict__ Wout,
    const float* __restrict__ W1, const float* __restrict__ W2,
    u16* __restrict__ WqkvT, u16* __restrict__ WoutT,
    u16* __restrict__ W1T, u16* __restrict__ W2T) {
  int id = blockIdx.x;
  const float* in; u16* out; int K, N, nx, base;
  if (id < 3072)      { in = Wqkv; out = WqkvT; K = 1024; N = 3072; nx = 96;  base = 0; }
  else if (id < 4096) { in = Wout; out = WoutT; K = 1024; N = 1024; nx = 32;  base = 3072; }
  else if (id < 8192) { in = W1;   out = W1T;   K = 1024; N = 4096; nx = 128; base = 4096; }
  else                { in = W2;   out = W2T;   K = 4096; N = 1024; nx = 32;  base = 8192; }
  int seg = id - base, bx = seg % nx, by = seg / nx;
  __shared__ float tile[32][33];
  int tx = threadIdx.x & 31, ty = threadIdx.x >> 5;  // 32 x 8
#pragma unroll
  for (int r = 0; r < 32; r += 8)
    tile[ty + r][tx] = in[(size_t)(by * 32 + ty + r) * N + bx * 32 + tx];
  __syncthreads();
#pragma unroll
  for (int r = 0; r < 32; r += 8)
    out[(size_t)(bx * 32 + ty + r) * K + by * 32 + tx] = f2bf(tile[tx][ty + r]);
}

// ---------------- LayerNorm: x [rows][1024] f32 -> out bf16 ------------------
__global__ __launch_bounds__(256) void k_layernorm(
    const float* __restrict__ x, const float* __restrict__ gamma,
    const float* __restrict__ beta, u16* __restrict__ out) {
  int row = blockIdx.x, t = threadIdx.x;
  const float4 v = ((const float4*)(x + (size_t)row * 1024))[t];
  float sum = v.x + v.y + v.z + v.w;
  float sq = v.x * v.x + v.y * v.y + v.z * v.z + v.w * v.w;
#pragma unroll
  for (int o = 32; o >= 1; o >>= 1) {
    sum += __shfl_down(sum, o);
    sq += __shfl_down(sq, o);
  }
  __shared__ float red[8];
  if ((t & 63) == 0) { red[(t >> 6) * 2] = sum; red[(t >> 6) * 2 + 1] = sq; }
  __syncthreads();
  sum = red[0] + red[2] + red[4] + red[6];
  sq = red[1] + red[3] + red[5] + red[7];
  float mean = sum * (1.0f / 1024.0f);
  float var = sq * (1.0f / 1024.0f) - mean * mean;
  float rstd = rsqrtf(var + 1e-5f);
  float4 g = ((const float4*)gamma)[t];
  float4 b = ((const float4*)beta)[t];
  ushort4 o4;
  o4.x = f2bf(g.x * (v.x - mean) * rstd + b.x);
  o4.y = f2bf(g.y * (v.y - mean) * rstd + b.y);
  o4.z = f2bf(g.z * (v.z - mean) * rstd + b.z);
  o4.w = f2bf(g.w * (v.w - mean) * rstd + b.w);
  ((ushort4*)(out + (size_t)row * 1024))[t] = o4;
}

// ---------------- epilogues (r = M row; c0 = first of 4 consecutive N) -------
struct EpiQKV {  // scatter qkv: Q,K [B*H][S][64] bf16 ; VT [B*H][64][S] bf16
  u16 *Q, *K2, *VT;
  DEV void operator()(int r, int c0, const f32x4& v) const {
    int three = c0 >> 10, h = (c0 >> 6) & 15, hd = c0 & 63;
    int b = r >> 11, s = r & 2047;
    int bh = b * 16 + h;
    ushort4 o;
    o.x = f2bf(v[0]); o.y = f2bf(v[1]); o.z = f2bf(v[2]); o.w = f2bf(v[3]);
    if (three == 0)
      *(ushort4*)&Q[((size_t)bh * 2048 + s) * 64 + hd] = o;
    else if (three == 1)
      *(ushort4*)&K2[((size_t)bh * 2048 + s) * 64 + hd] = o;
    else {
      VT[((size_t)bh * 64 + hd + 0) * 2048 + s] = o.x;
      VT[((size_t)bh * 64 + hd + 1) * 2048 + s] = o.y;
      VT[((size_t)bh * 64 + hd + 2) * 2048 + s] = o.z;
      VT[((size_t)bh * 64 + hd + 3) * 2048 + s] = o.w;
    }
  }
};

struct EpiBiasResid {  // out f32 = v + bias[c] + resid[r*N+c]
  const float* bias; const float* resid; float* out; int N;
  DEV void operator()(int r, int c0, const f32x4& v) const {
    size_t idx = (size_t)r * N + c0;
    float4 bb = *(const float4*)&bias[c0];
    float4 rr = *(const float4*)&resid[idx];
    float4 o;
    o.x = v[0] + bb.x + rr.x; o.y = v[1] + bb.y + rr.y;
    o.z = v[2] + bb.z + rr.z; o.w = v[3] + bb.w + rr.w;
    *(float4*)&out[idx] = o;
  }
};

struct EpiBiasGelu {  // out bf16 = gelu_tanh(v + bias[c])
  const float* bias; u16* out; int N;
  DEV float gelu(float xx) const {
    float u = 0.7978845608f * (xx + 0.044715f * xx * xx * xx);
    float e = __expf(2.0f * u);
    float th = 1.0f - 2.0f / (e + 1.0f);
    return 0.5f * xx * (1.0f + th);
  }
  DEV void operator()(int r, int c0, const f32x4& v) const {
    float4 bb = *(const float4*)&bias[c0];
    ushort4 o;
    o.x = f2bf(gelu(v[0] + bb.x)); o.y = f2bf(gelu(v[1] + bb.y));
    o.z = f2bf(gelu(v[2] + bb.z)); o.w = f2bf(gelu(v[3] + bb.w));
    *(ushort4*)&out[(size_t)r * N + c0] = o;
  }
};

// ---------------- GEMM TN: A[M,K] bf16 K-contig, Bt[N,K] bf16 K-contig -------
// 128x128 tile, 256 thr (4 waves 2x2), BK=64 as TWO 32-K panels, DEPTH-2 dbuf
// (r5/r6-verified).  r8 lesson: do NOT XCD-remap this grid — bm-fastest
// dispatch makes co-scheduled blocks share the same bn band, so A streams
// through HBM once for the whole machine; the remap cost 4.5x FETCH_SIZE.
#define STG8(tk, d) do { \
    GLDS(gA + (tk) * 64,                        &As[d][0][t * 8]); \
    GLDS(gA + (tk) * 64 + (size_t)64 * K,       &As[d][0][t * 8 + 2048]); \
    GLDS(gA + (tk) * 64 + 32,                   &As[d][1][t * 8]); \
    GLDS(gA + (tk) * 64 + 32 + (size_t)64 * K,  &As[d][1][t * 8 + 2048]); \
    GLDS(gB + (tk) * 64,                        &Bs[d][0][t * 8]); \
    GLDS(gB + (tk) * 64 + (size_t)64 * K,       &Bs[d][0][t * 8 + 2048]); \
    GLDS(gB + (tk) * 64 + 32,                   &Bs[d][1][t * 8]); \
    GLDS(gB + (tk) * 64 + 32 + (size_t)64 * K,  &Bs[d][1][t * 8 + 2048]); \
  } while (0)

template <typename Epi>
__global__ __launch_bounds__(256) void k_gemm_tn(
    const u16* __restrict__ A, const u16* __restrict__ Bt, int K, Epi epi) {
  __shared__ u16 As[2][2][128 * 32];  // [dbuf][panel][row*32+k], 32 KB
  __shared__ u16 Bs[2][2][128 * 32];  // 32 KB  -> 64 KB total
  const int t = threadIdx.x;
  const int bm = blockIdx.x, bn = blockIdx.y;
  const int lane = t & 63, w = t >> 6;
  const int wm = w >> 1, wn = w & 1;
  const int quad = lane >> 4, l16 = lane & 15;
  f32x4 acc[4][4] = {};
  const u16* gA = A + (size_t)(bm * 128 + (t >> 2)) * K + (t & 3) * 8;
  const u16* gB = Bt + (size_t)(bn * 128 + (t >> 2)) * K + (t & 3) * 8;
  const int NT = K >> 6;  // K % 64 == 0; NT >= 2

  STG8(0, 0);
  STG8(1, 1);
  VMW(8);
  BAR();

  for (int T = 0; T < NT; ++T) {
    const int d = T & 1;
#pragma unroll
    for (int kk = 0; kk < 2; ++kk) {
      bf16x8 af[4], bfr[4];
#pragma unroll
      for (int mt = 0; mt < 4; ++mt)
        af[mt] = *(const bf16x8*)&As[d][kk][(wm * 64 + mt * 16 + l16) * 32 + quad * 8];
#pragma unroll
      for (int nt = 0; nt < 4; ++nt)
        bfr[nt] = *(const bf16x8*)&Bs[d][kk][(wn * 64 + nt * 16 + l16) * 32 + quad * 8];
#pragma unroll
      for (int mt = 0; mt < 4; ++mt)
#pragma unroll
        for (int nt = 0; nt < 4; ++nt)
          acc[mt][nt] = __builtin_amdgcn_mfma_f32_16x16x32_bf16(
              bfr[nt], af[mt], acc[mt][nt], 0, 0, 0);
    }
    SCHED0();
    BAR();      // all waves done reading buf[d]
    SCHED0();
    if (T + 2 < NT) {
      STG8(T + 2, d);   // overwrite buf[d] with tile T+2
      VMW(8);           // drain tile T+1 (issued one full iteration ago)
    } else {
      VMW(0);           // tail
    }
    BAR();
  }

  const int r0 = bm * 128 + wm * 64 + l16;       // M
  const int c0 = bn * 128 + wn * 64 + quad * 4;  // N (4 consecutive per lane)
#pragma unroll
  for (int mt = 0; mt < 4; ++mt)
#pragma unroll
    for (int nt = 0; nt < 4; ++nt)
      epi(r0 + mt * 16, c0 + nt * 16, acc[mt][nt]);
}

// ---------------- causal flash attention (S^T form, no-max online softmax) ---
// T14 async-STAGE split (r6 verified): K/V(kt+1) global->reg loads issue during
// tile kt's compute; VMW(0) lands them at the next write point.  r9 lesson:
// setprio (m190: harmful on barrier-lockstep structures) and lone inline-asm
// cvt_pk (m240: -37% vs scalar casts) both REGRESSED here -- reverted.
#define PW 72  // u16 row stride: 144 B; 2-way banks on b128 reads (free)

#define ATT_LOAD(kr, vr, k0_) do { \
  _Pragma("unroll") for (int j = 0; j < 4; ++j) { \
    int ch = t + 256 * j, r = ch >> 4, cc = (ch & 15) * 4; \
    kr[j] = *(const u64*)(Kbase + (size_t)((k0_) + r) * 64 + cc); \
    vr[j] = *(const u64*)(Vbase + (size_t)r * 2048 + (k0_) + cc); \
  } } while (0)

#define ATT_WRITE(kr, vr) do { \
  _Pragma("unroll") for (int j = 0; j < 4; ++j) { \
    int ch = t + 256 * j, r = ch >> 4, cc = (ch & 15) * 4; \
    *(u64*)&Ks[r * PW + cc] = kr[j]; \
    *(u64*)&Vs[r * PW + cc] = vr[j]; \
  } } while (0)

__global__ __launch_bounds__(256) void k_attn(
    const u16* __restrict__ Qg, const u16* __restrict__ Kg,
    const u16* __restrict__ VTg, u16* __restrict__ ctx) {
  const int bh = blockIdx.x;
  const int qt = 31 - blockIdx.y;  // big blocks first for tail scheduling
  const int b = bh >> 4, h = bh & 15;
  const int t = threadIdx.x, lane = t & 63, w = t >> 6;
  const int quad = lane >> 4, l16 = lane & 15;
  const int q0 = qt * 64;
  __shared__ u16 Qs[64 * PW], Ks[64 * PW], Vs[64 * PW];
  __shared__ u16 Ps[4][16 * PW];
  __shared__ float l_lds[4][16];
  const u16* Qbase = Qg + (size_t)bh * (2048 * 64);
  const u16* Kbase = Kg + (size_t)bh * (2048 * 64);
  const u16* Vbase = VTg + (size_t)bh * (64 * 2048);
#pragma unroll
  for (int j = 0; j < 4; ++j) {
    int ch = t + 256 * j, r = ch >> 4, cc = (ch & 15) * 4;
    *(u64*)&Qs[r * PW + cc] = *(const u64*)(Qbase + (size_t)(q0 + r) * 64 + cc);
  }
  __syncthreads();
  bf16x8 qf0 = *(const bf16x8*)&Qs[(w * 16 + l16) * PW + quad * 8];
  bf16x8 qf1 = *(const bf16x8*)&Qs[(w * 16 + l16) * PW + 32 + quad * 8];
  const int qrow = q0 + w * 16 + l16;  // one q-row per lane
  const float c1 = 0.18033688011f;     // (1/8) * log2(e)
  float lsum = 0.f;
  f32x4 acco[4] = {};

  auto tile = [&](int kt) {
    const int k0 = kt * 64;
    f32x4 sacc[4] = {};
#pragma unroll
    for (int kk = 0; kk < 2; ++kk) {
      bf16x8 qf = kk ? qf1 : qf0;
#pragma unroll
      for (int nt = 0; nt < 4; ++nt) {
        bf16x8 kf = *(const bf16x8*)&Ks[(nt * 16 + l16) * PW + kk * 32 + quad * 8];
        sacc[nt] = __builtin_amdgcn_mfma_f32_16x16x32_bf16(kf, qf, sacc[nt], 0, 0, 0);
      }
    }
    const bool diag = (kt == qt);
    float ls = 0.f;
#pragma unroll
    for (int nt = 0; nt < 4; ++nt) {
      ushort4 o;
#pragma unroll
      for (int reg = 0; reg < 4; ++reg) {
        float p = __builtin_amdgcn_exp2f(sacc[nt][reg] * c1);  // bounded scores
        if (diag && (k0 + nt * 16 + quad * 4 + reg > qrow)) p = 0.f;
        ls += p;
        (&o.x)[reg] = f2bf(p);
      }
      *(ushort4*)&Ps[w][l16 * PW + nt * 16 + quad * 4] = o;  // P^T -> A-layout
    }
    ls += __shfl_xor(ls, 16);
    ls += __shfl_xor(ls, 32);
    lsum += ls;
#pragma unroll
    for (int kk = 0; kk < 2; ++kk) {
      bf16x8 pf = *(const bf16x8*)&Ps[w][l16 * PW + kk * 32 + quad * 8];
#pragma unroll
      for (int nt = 0; nt < 4; ++nt) {
        bf16x8 vf = *(const bf16x8*)&Vs[(nt * 16 + l16) * PW + kk * 32 + quad * 8];
        acco[nt] = __builtin_amdgcn_mfma_f32_16x16x32_bf16(pf, vf, acco[nt], 0, 0, 0);
      }
    }
  };

  u64 kra[4], vra[4], krb[4], vrb[4];
  ATT_LOAD(kra, vra, 0);
  int kt = 0;
  while (true) {
    VMW(0);             // set-a data landed (issued a full tile earlier)
    BAR();              // all waves done reading Ks/Vs from prev tile
    ATT_WRITE(kra, vra);
    if (kt + 1 <= qt) ATT_LOAD(krb, vrb, (kt + 1) * 64);  // prefetch, in flight
    LGKM0();            // ds_writes visible
    BAR();
    tile(kt);
    if (++kt > qt) break;
    VMW(0);
    BAR();
    ATT_WRITE(krb, vrb);
    if (kt + 1 <= qt) ATT_LOAD(kra, vra, (kt + 1) * 64);
    LGKM0();
    BAR();
    tile(kt);
    if (++kt > qt) break;
  }

  if (quad == 0) l_lds[w][l16] = lsum;  // same-wave DS ops are ordered
  float4 lv = *(const float4*)&l_lds[w][quad * 4];
  float inv[4];
  inv[0] = 1.0f / lv.x; inv[1] = 1.0f / lv.y;
  inv[2] = 1.0f / lv.z; inv[3] = 1.0f / lv.w;
#pragma unroll
  for (int nt = 0; nt < 4; ++nt)
#pragma unroll
    for (int reg = 0; reg < 4; ++reg) {
      float o = acco[nt][reg] * inv[reg];
      int q = q0 + w * 16 + quad * 4 + reg;
      ctx[((size_t)(b * 2048 + q)) * 1024 + h * 64 + nt * 16 + l16] = f2bf(o);
    }
}

// ---------------- orchestration ----------------------------------------------
extern "C" void kernel_launch(void* const* d_in, const int* in_sizes, int n_in,
                              void* d_out, int out_size, void* d_ws, size_t ws_size,
                              hipStream_t stream) {
  (void)in_sizes; (void)n_in; (void)out_size; (void)ws_size;
  const float* x    = (const float*)d_in[0];
  const float* Wqkv = (const float*)d_in[1];
  const float* Wout = (const float*)d_in[2];
  const float* bout = (const float*)d_in[3];
  const float* W1   = (const float*)d_in[4];
  const float* b1   = (const float*)d_in[5];
  const float* W2   = (const float*)d_in[6];
  const float* b2   = (const float*)d_in[7];
  const float* g1   = (const float*)d_in[8];
  const float* s1   = (const float*)d_in[9];
  const float* g2   = (const float*)d_in[10];
  const float* s2   = (const float*)d_in[11];

  char* ws = (char*)d_ws;
  u16*   WqkvT = (u16*)(ws + 0);           //  6291456 B
  u16*   WoutT = (u16*)(ws + 6291456);     //  2097152
  u16*   W1T   = (u16*)(ws + 8388608);     //  8388608
  u16*   W2T   = (u16*)(ws + 16777216);    //  8388608
  float* x1    = (float*)(ws + 25165824);  // 33554432
  u16*   h12   = (u16*)(ws + 58720256);    // 16777216  (h1, later h2)
  u16*   Qb    = (u16*)(ws + 75497472);    // 16777216
  u16*   Kb    = (u16*)(ws + 92274688);    // 16777216
  u16*   VTb   = (u16*)(ws + 109051904);   // 16777216
  u16*   ctx   = (u16*)(ws + 125829120);   // 16777216  -> total 142606336
  u16*   a1    = (u16*)(ws + 75497472);    // 67108864, aliases Q..ctx (dead)

  k_transpose_all<<<12288, 256, 0, stream>>>(Wqkv, Wout, W1, W2,
                                             WqkvT, WoutT, W1T, W2T);

  k_layernorm<<<8192, 256, 0, stream>>>(x, g1, s1, h12);
  k_gemm_tn<<<dim3(64, 24), 256, 0, stream>>>(h12, WqkvT, 1024,
                                              EpiQKV{Qb, Kb, VTb});
  k_attn<<<dim3(64, 32), 256, 0, stream>>>(Qb, Kb, VTb, ctx);
  k_gemm_tn<<<dim3(64, 8), 256, 0, stream>>>(ctx, WoutT, 1024,
                                             EpiBiasResid{bout, x, x1, 1024});
  k_layernorm<<<8192, 256, 0, stream>>>(x1, g2, s2, h12);
  k_gemm_tn<<<dim3(64, 32), 256, 0, stream>>>(h12, W1T, 1024,
                                              EpiBiasGelu{b1, a1, 4096});
  k_gemm_tn<<<dim3(64, 8), 256, 0, stream>>>(a1, W2T, 4096,
                                             EpiBiasResid{b2, x1, (float*)d_out, 1024});
}

// Round 12
// 516.612 us; speedup vs baseline: 1.0735x; 1.0129x over previous
//
#include <hip/hip_runtime.h>
#include <stdint.h>

typedef unsigned short u16;
typedef unsigned long long u64;
typedef __attribute__((ext_vector_type(8))) short bf16x8;
typedef __attribute__((ext_vector_type(4))) float f32x4;

#define DEV __device__ __forceinline__

DEV u16 f2bf(float f) {
  union { float f; unsigned u; } v; v.f = f;
  unsigned r = (v.u + 0x7fffu + ((v.u >> 16) & 1u)) >> 16;
  return (u16)r;
}

#define GLDS(g, l) __builtin_amdgcn_global_load_lds( \
    (const __attribute__((address_space(1))) void*)(g), \
    (__attribute__((address_space(3))) void*)(l), 16, 0, 0)

#define BAR() __builtin_amdgcn_s_barrier()
#define LGKM0() asm volatile("s_waitcnt lgkmcnt(0)" ::: "memory")
#define VMW(n) asm volatile("s_waitcnt vmcnt(" #n ")" ::: "memory")
#define SCHED0() __builtin_amdgcn_sched_barrier(0)

// ------- fused weight transpose+cast: [K][N] f32 -> [N][K] bf16, 4 segments --
__global__ __launch_bounds__(256) void k_transpose_all(
    const float* __restrict__ Wqkv, const float* __restrict__ Wout,
    const float* __restrict__ W1, const float* __restrict__ W2,
    u16* __restrict__ WqkvT, u16* __restrict__ WoutT,
    u16* __restrict__ W1T, u16* __restrict__ W2T) {
  int id = blockIdx.x;
  const float* in; u16* out; int K, N, nx, base;
  if (id < 3072)      { in = Wqkv; out = WqkvT; K = 1024; N = 3072; nx = 96;  base = 0; }
  else if (id < 4096) { in = Wout; out = WoutT; K = 1024; N = 1024; nx = 32;  base = 3072; }
  else if (id < 8192) { in = W1;   out = W1T;   K = 1024; N = 4096; nx = 128; base = 4096; }
  else                { in = W2;   out = W2T;   K = 4096; N = 1024; nx = 32;  base = 8192; }
  int seg = id - base, bx = seg % nx, by = seg / nx;
  __shared__ float tile[32][33];
  int tx = threadIdx.x & 31, ty = threadIdx.x >> 5;  // 32 x 8
#pragma unroll
  for (int r = 0; r < 32; r += 8)
    tile[ty + r][tx] = in[(size_t)(by * 32 + ty + r) * N + bx * 32 + tx];
  __syncthreads();
#pragma unroll
  for (int r = 0; r < 32; r += 8)
    out[(size_t)(bx * 32 + ty + r) * K + by * 32 + tx] = f2bf(tile[tx][ty + r]);
}

// ---------------- LayerNorm: x [rows][1024] f32 -> out bf16 ------------------
__global__ __launch_bounds__(256) void k_layernorm(
    const float* __restrict__ x, const float* __restrict__ gamma,
    const float* __restrict__ beta, u16* __restrict__ out) {
  int row = blockIdx.x, t = threadIdx.x;
  const float4 v = ((const float4*)(x + (size_t)row * 1024))[t];
  float sum = v.x + v.y + v.z + v.w;
  float sq = v.x * v.x + v.y * v.y + v.z * v.z + v.w * v.w;
#pragma unroll
  for (int o = 32; o >= 1; o >>= 1) {
    sum += __shfl_down(sum, o);
    sq += __shfl_down(sq, o);
  }
  __shared__ float red[8];
  if ((t & 63) == 0) { red[(t >> 6) * 2] = sum; red[(t >> 6) * 2 + 1] = sq; }
  __syncthreads();
  sum = red[0] + red[2] + red[4] + red[6];
  sq = red[1] + red[3] + red[5] + red[7];
  float mean = sum * (1.0f / 1024.0f);
  float var = sq * (1.0f / 1024.0f) - mean * mean;
  float rstd = rsqrtf(var + 1e-5f);
  float4 g = ((const float4*)gamma)[t];
  float4 b = ((const float4*)beta)[t];
  ushort4 o4;
  o4.x = f2bf(g.x * (v.x - mean) * rstd + b.x);
  o4.y = f2bf(g.y * (v.y - mean) * rstd + b.y);
  o4.z = f2bf(g.z * (v.z - mean) * rstd + b.z);
  o4.w = f2bf(g.w * (v.w - mean) * rstd + b.w);
  ((ushort4*)(out + (size_t)row * 1024))[t] = o4;
}

// ---------------- epilogues (r = M row; c0 = first of 4 consecutive N) -------
struct EpiQKV {  // scatter qkv: Q,K [B*H][S][64] bf16 ; VT [B*H][64][S] bf16
  u16 *Q, *K2, *VT;
  DEV void operator()(int r, int c0, const f32x4& v) const {
    int three = c0 >> 10, h = (c0 >> 6) & 15, hd = c0 & 63;
    int b = r >> 11, s = r & 2047;
    int bh = b * 16 + h;
    ushort4 o;
    o.x = f2bf(v[0]); o.y = f2bf(v[1]); o.z = f2bf(v[2]); o.w = f2bf(v[3]);
    if (three == 0)
      *(ushort4*)&Q[((size_t)bh * 2048 + s) * 64 + hd] = o;
    else if (three == 1)
      *(ushort4*)&K2[((size_t)bh * 2048 + s) * 64 + hd] = o;
    else {
      VT[((size_t)bh * 64 + hd + 0) * 2048 + s] = o.x;
      VT[((size_t)bh * 64 + hd + 1) * 2048 + s] = o.y;
      VT[((size_t)bh * 64 + hd + 2) * 2048 + s] = o.z;
      VT[((size_t)bh * 64 + hd + 3) * 2048 + s] = o.w;
    }
  }
};

struct EpiBiasResid {  // out f32 = v + bias[c] + resid[r*N+c]
  const float* bias; const float* resid; float* out; int N;
  DEV void operator()(int r, int c0, const f32x4& v) const {
    size_t idx = (size_t)r * N + c0;
    float4 bb = *(const float4*)&bias[c0];
    float4 rr = *(const float4*)&resid[idx];
    float4 o;
    o.x = v[0] + bb.x + rr.x; o.y = v[1] + bb.y + rr.y;
    o.z = v[2] + bb.z + rr.z; o.w = v[3] + bb.w + rr.w;
    *(float4*)&out[idx] = o;
  }
};

struct EpiBiasGelu {  // out bf16 = gelu_tanh(v + bias[c])
  const float* bias; u16* out; int N;
  DEV float gelu(float xx) const {
    float u = 0.7978845608f * (xx + 0.044715f * xx * xx * xx);
    float e = __expf(2.0f * u);
    float th = 1.0f - 2.0f / (e + 1.0f);
    return 0.5f * xx * (1.0f + th);
  }
  DEV void operator()(int r, int c0, const f32x4& v) const {
    float4 bb = *(const float4*)&bias[c0];
    ushort4 o;
    o.x = f2bf(gelu(v[0] + bb.x)); o.y = f2bf(gelu(v[1] + bb.y));
    o.z = f2bf(gelu(v[2] + bb.z)); o.w = f2bf(gelu(v[3] + bb.w));
    *(ushort4*)&out[(size_t)r * N + c0] = o;
  }
};

// ---------------- GEMM TN 128x128 (QKV, Wout, W2) ----------------------------
// 256 thr (4 waves 2x2), BK=64 as TWO 32-K panels, DEPTH-2 dbuf (r5-verified).
// r8 lesson: do NOT XCD-remap — bm-fastest dispatch keeps co-scheduled blocks
// in the same bn band (A streams from HBM once; remap cost 4.5x FETCH_SIZE).
#define STG8(tk, d) do { \
    GLDS(gA + (tk) * 64,                        &As[d][0][t * 8]); \
    GLDS(gA + (tk) * 64 + (size_t)64 * K,       &As[d][0][t * 8 + 2048]); \
    GLDS(gA + (tk) * 64 + 32,                   &As[d][1][t * 8]); \
    GLDS(gA + (tk) * 64 + 32 + (size_t)64 * K,  &As[d][1][t * 8 + 2048]); \
    GLDS(gB + (tk) * 64,                        &Bs[d][0][t * 8]); \
    GLDS(gB + (tk) * 64 + (size_t)64 * K,       &Bs[d][0][t * 8 + 2048]); \
    GLDS(gB + (tk) * 64 + 32,                   &Bs[d][1][t * 8]); \
    GLDS(gB + (tk) * 64 + 32 + (size_t)64 * K,  &Bs[d][1][t * 8 + 2048]); \
  } while (0)

template <typename Epi>
__global__ __launch_bounds__(256) void k_gemm_tn(
    const u16* __restrict__ A, const u16* __restrict__ Bt, int K, Epi epi) {
  __shared__ u16 As[2][2][128 * 32];  // [dbuf][panel][row*32+k], 32 KB
  __shared__ u16 Bs[2][2][128 * 32];  // 32 KB  -> 64 KB total
  const int t = threadIdx.x;
  const int bm = blockIdx.x, bn = blockIdx.y;
  const int lane = t & 63, w = t >> 6;
  const int wm = w >> 1, wn = w & 1;
  const int quad = lane >> 4, l16 = lane & 15;
  f32x4 acc[4][4] = {};
  const u16* gA = A + (size_t)(bm * 128 + (t >> 2)) * K + (t & 3) * 8;
  const u16* gB = Bt + (size_t)(bn * 128 + (t >> 2)) * K + (t & 3) * 8;
  const int NT = K >> 6;  // K % 64 == 0; NT >= 2

  STG8(0, 0);
  STG8(1, 1);
  VMW(8);
  BAR();

  for (int T = 0; T < NT; ++T) {
    const int d = T & 1;
#pragma unroll
    for (int kk = 0; kk < 2; ++kk) {
      bf16x8 af[4], bfr[4];
#pragma unroll
      for (int mt = 0; mt < 4; ++mt)
        af[mt] = *(const bf16x8*)&As[d][kk][(wm * 64 + mt * 16 + l16) * 32 + quad * 8];
#pragma unroll
      for (int nt = 0; nt < 4; ++nt)
        bfr[nt] = *(const bf16x8*)&Bs[d][kk][(wn * 64 + nt * 16 + l16) * 32 + quad * 8];
#pragma unroll
      for (int mt = 0; mt < 4; ++mt)
#pragma unroll
        for (int nt = 0; nt < 4; ++nt)
          acc[mt][nt] = __builtin_amdgcn_mfma_f32_16x16x32_bf16(
              bfr[nt], af[mt], acc[mt][nt], 0, 0, 0);
    }
    SCHED0();
    BAR();      // all waves done reading buf[d]
    SCHED0();
    if (T + 2 < NT) {
      STG8(T + 2, d);   // overwrite buf[d] with tile T+2
      VMW(8);           // drain tile T+1 (issued one full iteration ago)
    } else {
      VMW(0);           // tail
    }
    BAR();
  }

  const int r0 = bm * 128 + wm * 64 + l16;       // M
  const int c0 = bn * 128 + wn * 64 + quad * 4;  // N (4 consecutive per lane)
#pragma unroll
  for (int mt = 0; mt < 4; ++mt)
#pragma unroll
    for (int nt = 0; nt < 4; ++nt)
      epi(r0 + mt * 16, c0 + nt * 16, acc[mt][nt]);
}

// ---------------- GEMM TN 256x256 (W1 only: 512 blocks = 2 exact rounds) -----
// r7-measured 115.4 us for this shape (vs 122 at 128^2).  Same depth-2
// 2-barrier schedule; 8 waves (2Mx4N), per-wave 128x64, acc[8][4], LDS 128 KB.
#define STG8W(tk, d) do { \
    GLDS(gA + (tk) * 64,                         &As[d][0][t * 8]); \
    GLDS(gA + (tk) * 64 + (size_t)128 * K,       &As[d][0][t * 8 + 4096]); \
    GLDS(gA + (tk) * 64 + 32,                    &As[d][1][t * 8]); \
    GLDS(gA + (tk) * 64 + 32 + (size_t)128 * K,  &As[d][1][t * 8 + 4096]); \
    GLDS(gB + (tk) * 64,                         &Bs[d][0][t * 8]); \
    GLDS(gB + (tk) * 64 + (size_t)128 * K,       &Bs[d][0][t * 8 + 4096]); \
    GLDS(gB + (tk) * 64 + 32,                    &Bs[d][1][t * 8]); \
    GLDS(gB + (tk) * 64 + 32 + (size_t)128 * K,  &Bs[d][1][t * 8 + 4096]); \
  } while (0)

template <typename Epi>
__global__ __launch_bounds__(512, 2) void k_gemm_wide(
    const u16* __restrict__ A, const u16* __restrict__ Bt, int K, Epi epi) {
  __shared__ u16 As[2][2][256 * 32];  // 64 KB
  __shared__ u16 Bs[2][2][256 * 32];  // 64 KB -> 128 KB total
  const int t = threadIdx.x;
  const int bm = blockIdx.x, bn = blockIdx.y;
  const int lane = t & 63, w = t >> 6;
  const int wm = w >> 2, wn = w & 3;   // 2 x 4 waves; wave tile 128 x 64
  const int quad = lane >> 4, l16 = lane & 15;
  f32x4 acc[8][4] = {};
  const u16* gA = A + (size_t)(bm * 256 + (t >> 2)) * K + (t & 3) * 8;
  const u16* gB = Bt + (size_t)(bn * 256 + (t >> 2)) * K + (t & 3) * 8;
  const int NT = K >> 6;

  STG8W(0, 0);
  STG8W(1, 1);
  VMW(8);
  BAR();

  for (int T = 0; T < NT; ++T) {
    const int d = T & 1;
#pragma unroll
    for (int kk = 0; kk < 2; ++kk) {
      bf16x8 af[8], bfr[4];
#pragma unroll
      for (int mt = 0; mt < 8; ++mt)
        af[mt] = *(const bf16x8*)&As[d][kk][(wm * 128 + mt * 16 + l16) * 32 + quad * 8];
#pragma unroll
      for (int nt = 0; nt < 4; ++nt)
        bfr[nt] = *(const bf16x8*)&Bs[d][kk][(wn * 64 + nt * 16 + l16) * 32 + quad * 8];
#pragma unroll
      for (int mt = 0; mt < 8; ++mt)
#pragma unroll
        for (int nt = 0; nt < 4; ++nt)
          acc[mt][nt] = __builtin_amdgcn_mfma_f32_16x16x32_bf16(
              bfr[nt], af[mt], acc[mt][nt], 0, 0, 0);
    }
    SCHED0();
    BAR();
    SCHED0();
    if (T + 2 < NT) {
      STG8W(T + 2, d);
      VMW(8);
    } else {
      VMW(0);
    }
    BAR();
  }

  const int r0 = bm * 256 + wm * 128 + l16;
  const int c0 = bn * 256 + wn * 64 + quad * 4;
#pragma unroll
  for (int mt = 0; mt < 8; ++mt)
#pragma unroll
    for (int nt = 0; nt < 4; ++nt)
      epi(r0 + mt * 16, c0 + nt * 16, acc[mt][nt]);
}

// ---------------- causal flash attention (S^T form, no-max online softmax) ---
// KVBLK=128 — one sync set (VMW+BAR+LGKM0+BAR) per TWO 64-K tiles.
// K LDS: 128 s-rows x 64 hd.  V LDS: two stacked [64 hd][64 s] sub-tiles
// (PW < 128 forbids a single 128-wide V row).  Q staged through Ks (alias);
// r12 hardening: LGKM0 after the qf reads guarantees each wave's Q ds_reads
// complete before it reaches the loop's first BAR (s_barrier orders execution,
// NOT outstanding DS ops — without this a pending Q-read could see another
// wave's K-write).  Single prefetch reg set reused in place: ds_write reads
// regs at issue; the following load's writeback cannot precede its own issue
// (in-order), and the compiler preserves the WAR dependency.  Tail (odd tile
// count): loads clamped to valid addresses, garbage rows written but never
// read (only tiles <= qt computed).  All branches block-uniform.
#define PW 72  // u16 row stride: 144 B; 2-way banks on b128 reads (free)

#define ATT_LOAD128(kr, vr, k0_) do { \
  _Pragma("unroll") for (int j = 0; j < 8; ++j) { \
    int ch = t + 256 * j, r = ch >> 4, cc = (ch & 15) * 4; \
    int krow = (k0_) + r; krow = krow < 2047 ? krow : 2047; \
    int vbase = (k0_) + (r >> 6) * 64; vbase = vbase < 1984 ? vbase : 1984; \
    kr[j] = *(const u64*)(Kbase + (size_t)krow * 64 + cc); \
    vr[j] = *(const u64*)(Vbase + (size_t)(r & 63) * 2048 + vbase + cc); \
  } } while (0)

#define ATT_WRITE128(kr, vr) do { \
  _Pragma("unroll") for (int j = 0; j < 8; ++j) { \
    int ch = t + 256 * j, r = ch >> 4, cc = (ch & 15) * 4; \
    *(u64*)&Ks[r * PW + cc] = kr[j]; \
    *(u64*)&Vs[r * PW + cc] = vr[j]; \
  } } while (0)

__global__ __launch_bounds__(256) void k_attn(
    const u16* __restrict__ Qg, const u16* __restrict__ Kg,
    const u16* __restrict__ VTg, u16* __restrict__ ctx) {
  const int bh = blockIdx.x;
  const int qt = 31 - blockIdx.y;  // big blocks first for tail scheduling
  const int b = bh >> 4, h = bh & 15;
  const int t = threadIdx.x, lane = t & 63, w = t >> 6;
  const int quad = lane >> 4, l16 = lane & 15;
  const int q0 = qt * 64;
  __shared__ u16 Ks[128 * PW], Vs[128 * PW];   // 18.4 KB each
  __shared__ u16 Ps[4][16 * PW];               // 9.2 KB
  __shared__ float l_lds[4][16];
  const u16* Qbase = Qg + (size_t)bh * (2048 * 64);
  const u16* Kbase = Kg + (size_t)bh * (2048 * 64);
  const u16* Vbase = VTg + (size_t)bh * (64 * 2048);
  // Q staged via Ks rows 0..63 (freed before first K write)
#pragma unroll
  for (int j = 0; j < 4; ++j) {
    int ch = t + 256 * j, r = ch >> 4, cc = (ch & 15) * 4;
    *(u64*)&Ks[r * PW + cc] = *(const u64*)(Qbase + (size_t)(q0 + r) * 64 + cc);
  }
  __syncthreads();
  bf16x8 qf0 = *(const bf16x8*)&Ks[(w * 16 + l16) * PW + quad * 8];
  bf16x8 qf1 = *(const bf16x8*)&Ks[(w * 16 + l16) * PW + 32 + quad * 8];
  LGKM0();   // r12: Q reads complete before this wave can reach the loop BAR
  const int qrow = q0 + w * 16 + l16;  // one q-row per lane
  const float c1 = 0.18033688011f;     // (1/8) * log2(e)
  float lsum = 0.f;
  f32x4 acco[4] = {};

  auto tile = [&](int kt, int off) {   // off = (kt & 1) * 64 row offset in LDS
    const int k0 = kt * 64;
    f32x4 sacc[4] = {};
#pragma unroll
    for (int kk = 0; kk < 2; ++kk) {
      bf16x8 qf = kk ? qf1 : qf0;
#pragma unroll
      for (int nt = 0; nt < 4; ++nt) {
        bf16x8 kf = *(const bf16x8*)&Ks[(off + nt * 16 + l16) * PW + kk * 32 + quad * 8];
        sacc[nt] = __builtin_amdgcn_mfma_f32_16x16x32_bf16(kf, qf, sacc[nt], 0, 0, 0);
      }
    }
    const bool diag = (kt == qt);
    float ls = 0.f;
#pragma unroll
    for (int nt = 0; nt < 4; ++nt) {
      ushort4 o;
#pragma unroll
      for (int reg = 0; reg < 4; ++reg) {
        float p = __builtin_amdgcn_exp2f(sacc[nt][reg] * c1);  // bounded scores
        if (diag && (k0 + nt * 16 + quad * 4 + reg > qrow)) p = 0.f;
        ls += p;
        (&o.x)[reg] = f2bf(p);
      }
      *(ushort4*)&Ps[w][l16 * PW + nt * 16 + quad * 4] = o;  // P^T -> A-layout
    }
    ls += __shfl_xor(ls, 16);
    ls += __shfl_xor(ls, 32);
    lsum += ls;
#pragma unroll
    for (int kk = 0; kk < 2; ++kk) {
      bf16x8 pf = *(const bf16x8*)&Ps[w][l16 * PW + kk * 32 + quad * 8];
#pragma unroll
      for (int nt = 0; nt < 4; ++nt) {
        bf16x8 vf = *(const bf16x8*)&Vs[(off + nt * 16 + l16) * PW + kk * 32 + quad * 8];
        acco[nt] = __builtin_amdgcn_mfma_f32_16x16x32_bf16(pf, vf, acco[nt], 0, 0, 0);
      }
    }
  };

  u64 kr[8], vr[8];
  ATT_LOAD128(kr, vr, 0);
  for (int p0 = 0; p0 <= qt; p0 += 2) {
    VMW(0);             // pair-p0 data landed (issued a full pair earlier)
    BAR();              // all waves done reading Ks/Vs (or Q) from before
    ATT_WRITE128(kr, vr);
    if (p0 + 2 <= qt) ATT_LOAD128(kr, vr, (p0 + 2) * 64);  // prefetch next pair
    LGKM0();            // ds_writes visible
    BAR();
    tile(p0, 0);
    if (p0 + 1 <= qt) tile(p0 + 1, 64);
  }

  if (quad == 0) l_lds[w][l16] = lsum;  // same-wave DS ops are ordered
  float4 lv = *(const float4*)&l_lds[w][quad * 4];
  float inv[4];
  inv[0] = 1.0f / lv.x; inv[1] = 1.0f / lv.y;
  inv[2] = 1.0f / lv.z; inv[3] = 1.0f / lv.w;
#pragma unroll
  for (int nt = 0; nt < 4; ++nt)
#pragma unroll
    for (int reg = 0; reg < 4; ++reg) {
      float o = acco[nt][reg] * inv[reg];
      int q = q0 + w * 16 + quad * 4 + reg;
      ctx[((size_t)(b * 2048 + q)) * 1024 + h * 64 + nt * 16 + l16] = f2bf(o);
    }
}

// ---------------- orchestration ----------------------------------------------
extern "C" void kernel_launch(void* const* d_in, const int* in_sizes, int n_in,
                              void* d_out, int out_size, void* d_ws, size_t ws_size,
                              hipStream_t stream) {
  (void)in_sizes; (void)n_in; (void)out_size; (void)ws_size;
  const float* x    = (const float*)d_in[0];
  const float* Wqkv = (const float*)d_in[1];
  const float* Wout = (const float*)d_in[2];
  const float* bout = (const float*)d_in[3];
  const float* W1   = (const float*)d_in[4];
  const float* b1   = (const float*)d_in[5];
  const float* W2   = (const float*)d_in[6];
  const float* b2   = (const float*)d_in[7];
  const float* g1   = (const float*)d_in[8];
  const float* s1   = (const float*)d_in[9];
  const float* g2   = (const float*)d_in[10];
  const float* s2   = (const float*)d_in[11];

  char* ws = (char*)d_ws;
  u16*   WqkvT = (u16*)(ws + 0);           //  6291456 B
  u16*   WoutT = (u16*)(ws + 6291456);     //  2097152
  u16*   W1T   = (u16*)(ws + 8388608);     //  8388608
  u16*   W2T   = (u16*)(ws + 16777216);    //  8388608
  float* x1    = (float*)(ws + 25165824);  // 33554432
  u16*   h12   = (u16*)(ws + 58720256);    // 16777216  (h1, later h2)
  u16*   Qb    = (u16*)(ws + 75497472);    // 16777216
  u16*   Kb    = (u16*)(ws + 92274688);    // 16777216
  u16*   VTb   = (u16*)(ws + 109051904);   // 16777216
  u16*   ctx   = (u16*)(ws + 125829120);   // 16777216  -> total 142606336
  u16*   a1    = (u16*)(ws + 75497472);    // 67108864, aliases Q..ctx (dead)

  k_transpose_all<<<12288, 256, 0, stream>>>(Wqkv, Wout, W1, W2,
                                             WqkvT, WoutT, W1T, W2T);

  k_layernorm<<<8192, 256, 0, stream>>>(x, g1, s1, h12);
  k_gemm_tn<<<dim3(64, 24), 256, 0, stream>>>(h12, WqkvT, 1024,
                                              EpiQKV{Qb, Kb, VTb});
  k_attn<<<dim3(64, 32), 256, 0, stream>>>(Qb, Kb, VTb, ctx);
  k_gemm_tn<<<dim3(64, 8), 256, 0, stream>>>(ctx, WoutT, 1024,
                                             EpiBiasResid{bout, x, x1, 1024});
  k_layernorm<<<8192, 256, 0, stream>>>(x1, g2, s2, h12);
  k_gemm_wide<<<dim3(32, 16), 512, 0, stream>>>(h12, W1T, 1024,
                                                EpiBiasGelu{b1, a1, 4096});
  k_gemm_tn<<<dim3(64, 8), 256, 0, stream>>>(a1, W2T, 4096,
                                             EpiBiasResid{b2, x1, (float*)d_out, 1024});
}